// Round 11
// baseline (219.989 us; speedup 1.0000x reference)
//
#include <hip/hip_runtime.h>

#define TOKENS 8192
#define IN_F   4096
#define OUT_F  4096

#define BM 256
#define BN 256
#define BK 64
#define NT (IN_F / BK)   // 64 K-tiles

typedef __attribute__((ext_vector_type(4))) float  f32x4;
typedef __attribute__((ext_vector_type(4))) int    i32x4;

// ---------------------------------------------------------------------------
// quant_x: per-token symmetric i8 quantization -> FRAGMENT-ORDER layout.
// A-granule (kt, g) = 1 KiB at aq[(kt*512 + g)*1024 + lane*16]:
//   lane l (lr=l&15, cg=l>>4) holds row g*16+lr, k = kt*64 + cg*16 .. +16.
// Block = one row-group g (16 rows). Pass 1: coalesced amax (16 thr/row,
// shfl reduce over low-4 lane bits). Pass 2: re-read (L2-hot 256KB tile) in
// frag pattern (64B segs), write perfectly coalesced 1 KiB granules:
// wave w covers kt = w*16 + s.
// ---------------------------------------------------------------------------
__global__ __launch_bounds__(256) void quant_x_kernel(const float* __restrict__ x,
                                                      signed char* __restrict__ aq,
                                                      float* __restrict__ dx) {
    const int g   = blockIdx.x;          // 0..511
    const int tid = threadIdx.x;
    const float* xr0 = x + (size_t)g * 16 * IN_F;

    // pass 1: amax. thread t: row r1 = t>>4, col-chunk c1 = t&15.
    const int r1 = tid >> 4;
    const int c1 = tid & 15;
    float m = 0.f;
    const float* p = xr0 + (size_t)r1 * IN_F + c1 * 4;
    for (int s = 0; s < 64; ++s) {
        f32x4 v = *(const f32x4*)(p + s * 64);
        m = fmaxf(fmaxf(fabsf(v[0]), fabsf(v[1])),
                  fmaxf(fmaxf(fabsf(v[2]), fabsf(v[3])), m));
    }
    // lanes differing only in low 4 bits share a row (lane = (r1&3)*16 + c1)
#pragma unroll
    for (int off = 1; off < 16; off <<= 1) m = fmaxf(m, __shfl_xor(m, off));
    __shared__ float sm[16];
    if (c1 == 0) sm[r1] = m;
    __syncthreads();
    if (tid < 16) dx[g * 16 + tid] = sm[tid] * (1.0f / 127.0f);

    // pass 2: quantize + frag-order write.
    const int lane = tid & 63, w = tid >> 6;
    const int lr = lane & 15, cg = lane >> 4;
    const float inv = 127.0f / sm[lr];
    const float* xp = xr0 + (size_t)lr * IN_F;
    signed char* outb = aq + (((size_t)(w * 16) * 512 + g) << 10) + lane * 16;

    for (int s = 0; s < 16; ++s) {
        const int kt = w * 16 + s;
        const f32x4* src = (const f32x4*)(xp + kt * 64 + cg * 16);
        i32x4 o;
#pragma unroll
        for (int k = 0; k < 4; ++k) {
            f32x4 v = src[k];
            int pk = 0;
#pragma unroll
            for (int j = 0; j < 4; ++j) {
                int q = (int)rintf(v[j] * inv);
                pk |= (q & 0xff) << (8 * j);
            }
            o[k] = pk;
        }
        *(i32x4*)(outb + ((size_t)s * 512 << 10)) = o;
    }
}

// ---------------------------------------------------------------------------
// quant_w: ternary -> i8 in fragment order (r10-verified).
// Granule (bn, kt, g) = 1 KiB at wq[((bn*64+kt)*16+g)*1024 + lane*16].
// ---------------------------------------------------------------------------
__global__ __launch_bounds__(256) void quant_w_kernel(const int* __restrict__ tern,
                                                      const float* __restrict__ scales,
                                                      signed char* __restrict__ wq,
                                                      float* __restrict__ dw) {
    const int o0   = blockIdx.x << 4;
    const int tid  = threadIdx.x;
    const int lane = tid & 63;
    const int lr   = lane & 15;
    const int lg   = lane >> 4;
    const int kt0  = tid >> 6;

    const int o = o0 + lr;
    const float* sr = scales + o * 32;
    float smax = 0.f;
#pragma unroll
    for (int g = 0; g < 32; ++g) smax = fmaxf(smax, sr[g]);
    const float rs = 127.0f / smax;
    if (tid < 16) dw[o0 + tid] = smax * (1.0f / 127.0f);

    const int bn  = o0 >> 8;
    const int g16 = (o0 >> 4) & 15;
    signed char* outb = wq + ((size_t)((bn * 64) * 16 + g16) << 10) + lane * 16;

#pragma unroll
    for (int i = 0; i < 16; ++i) {
        const int kt = kt0 * 16 + i;
        const int c  = kt * 4 + lg;
        const int iq = (int)rintf(sr[c >> 3] * rs);
        const i32x4* tp = (const i32x4*)(tern + (size_t)o * IN_F + c * 16);
        i32x4 w4;
#pragma unroll
        for (int k = 0; k < 4; ++k) {
            i32x4 tt = tp[k];
            int pk = 0;
#pragma unroll
            for (int j = 0; j < 4; ++j) pk |= ((tt[j] * iq) & 0xff) << (8 * j);
            w4[k] = pk;
        }
        *(i32x4*)(outb + ((size_t)(kt * 16) << 10)) = w4;
    }
}

// ---------------------------------------------------------------------------
// C = (xq . wq^T) * dx[m] * dw[n], i8 MFMA 16x16x64, i32 acc.
// r11: NO LDS, NO barriers, NO inline asm. 256x256 tile, 8 waves (2M x 4N),
// per-wave 128x64. Both operands in fragment order -> each frag is one
// coalesced 1 KiB global_load_dwordx4 (L1/L2-served: A reused 4x, B 2x
// within block; B panels L2-resident via bn-grouped XCD swizzle; A streams
// from L3). Double-buffered X/Y frags (unroll-2, static names, rule #20);
// compiler emits counted vmcnt. Waves fully independent -> natural dephasing
// hides VMEM latency under other waves' MFMAs (m114).
// Regs: acc 128 + frags 96 + addr ~ 240 < 256 (launch_bounds 512,2).
// ---------------------------------------------------------------------------

#define MFMA_ALL(AF, BF)                                                       \
  do {                                                                         \
    __builtin_amdgcn_s_setprio(1);                                             \
    _Pragma("unroll") for (int mi = 0; mi < 8; ++mi)                           \
      _Pragma("unroll") for (int ni = 0; ni < 4; ++ni)                         \
          acc[mi][ni] = __builtin_amdgcn_mfma_i32_16x16x64_i8(                 \
              AF[mi], BF[ni], acc[mi][ni], 0, 0, 0);                           \
    __builtin_amdgcn_s_setprio(0);                                             \
  } while (0)

#define LOADF(AF, BF, T)                                                       \
  do {                                                                         \
    _Pragma("unroll") for (int mi = 0; mi < 8; ++mi)                           \
        AF[mi] = *(const i32x4*)(aB + (((size_t)(T) * 512 + mi) << 10));       \
    _Pragma("unroll") for (int ni = 0; ni < 4; ++ni)                           \
        BF[ni] = *(const i32x4*)(bB + (((size_t)(T) * 16 + ni) << 10));        \
  } while (0)

__global__ __launch_bounds__(512, 2) void gemm_i8_kernel(
        const signed char* __restrict__ A,
        const signed char* __restrict__ B,
        const float* __restrict__ dX,
        const float* __restrict__ dW,
        float* __restrict__ C) {
    const int tid  = threadIdx.x;
    const int wave = tid >> 6;
    const int lane = tid & 63;
    const int wm   = wave >> 2;        // 0-1
    const int wn   = wave & 3;         // 0-3
    const int lg   = lane >> 4;        // 0-3
    const int lr   = lane & 15;        // 0-15

    // XCD swizzle, bn-grouped: XCD x owns bn {2x, 2x+1} (B L2-resident 2MB).
    const int bid = blockIdx.x;
    const int bn  = ((bid & 7) << 1) | (bid >> 8);   // 0..15
    const int bm  = (bid >> 3) & 31;                 // 0..31

    const size_t a_row0 = (size_t)bm * BM;
    const size_t b_row0 = (size_t)bn * BN;

    // fragment base pointers (this lane's 16B within each 1 KiB granule)
    const signed char* aB = A + (((size_t)(bm * 16 + wm * 8)) << 10) + lane * 16;
    const signed char* bB = B + (((size_t)(bn * 64 * 16 + wn * 4)) << 10) + lane * 16;

    i32x4 acc[8][4] = {};
    i32x4 aX[8], bX[4], aY[8], bY[4];

    LOADF(aX, bX, 0);
    LOADF(aY, bY, 1);

    for (int i = 0; i < NT / 2; ++i) {
        const int t0 = 2 * i;
        MFMA_ALL(aX, bX);
        if (t0 + 2 < NT) LOADF(aX, bX, t0 + 2);
        MFMA_ALL(aY, bY);
        if (t0 + 3 < NT) LOADF(aY, bY, t0 + 3);
    }

    // ---- epilogue: out = acc * dx[row] * dw[col]; C/D col=lane&15, row=lg*4+j
    float dwc[4];
#pragma unroll
    for (int ni = 0; ni < 4; ++ni) dwc[ni] = dW[b_row0 + wn * 64 + ni * 16 + lr];

    float* Cp = C + (a_row0 + wm * 128) * (size_t)OUT_F + b_row0 + wn * 64;
#pragma unroll
    for (int mi = 0; mi < 8; ++mi) {
#pragma unroll
        for (int j = 0; j < 4; ++j) {
            const int r = mi * 16 + lg * 4 + j;
            const float dxr = dX[a_row0 + wm * 128 + r];
#pragma unroll
            for (int ni = 0; ni < 4; ++ni)
                Cp[(size_t)r * OUT_F + ni * 16 + lr] =
                    (float)acc[mi][ni][j] * dxr * dwc[ni];
        }
    }
}

extern "C" void kernel_launch(void* const* d_in, const int* in_sizes, int n_in,
                              void* d_out, int out_size, void* d_ws, size_t ws_size,
                              hipStream_t stream) {
    const float* x      = (const float*)d_in[0];
    const int*   tern   = (const int*)d_in[1];
    const float* scales = (const float*)d_in[2];

    signed char* xq = (signed char*)d_ws;                  // 33.6 MB (frag order)
    signed char* wq = xq + (size_t)TOKENS * IN_F;          // 16.8 MB (frag order)
    float*       dx = (float*)(wq + (size_t)OUT_F * IN_F);
    float*       dw = dx + TOKENS;

    quant_x_kernel<<<TOKENS / 16, 256, 0, stream>>>(x, xq, dx);
    quant_w_kernel<<<OUT_F / 16, 256, 0, stream>>>(tern, scales, wq, dw);

    dim3 grid((TOKENS / BM) * (OUT_F / BN));   // 512
    gemm_i8_kernel<<<grid, 512, 0, stream>>>(xq, wq, dx, dw, (float*)d_out);
}